// Round 1
// baseline (132.312 us; speedup 1.0000x reference)
//
#include <hip/hip_runtime.h>

// Problem constants (from reference): N=4096, D=512, C=100, P=64
#define D 512
#define P 64
#define WPB 4           // waves per block -> block = 256 threads
#define EPS_COS 1e-8f
#define EPS_INV 1e-5f

__device__ __forceinline__ float wave_sum(float v) {
#pragma unroll
    for (int m = 32; m >= 1; m >>= 1) v += __shfl_xor(v, m, 64);
    return v;
}

__global__ __launch_bounds__(WPB * 64) void proto_probs_kernel(
    const float* __restrict__ feats,        // [N, D]
    const float* __restrict__ protos,       // [C, P, D]
    const int*   __restrict__ cls_ids,      // [N]
    const int*   __restrict__ proto_labels, // [C, P]
    float* __restrict__ out,                // [N] labels (as float) ++ [N, P] probs
    int N)
{
    const int lane = threadIdx.x & 63;
    const int wave = threadIdx.x >> 6;
    const int n = blockIdx.x * WPB + wave;
    if (n >= N) return;

    const int cls = cls_ids[n];
    const float* f  = feats  + (size_t)n * D;
    const float* pr = protos + (size_t)cls * (P * D);

    // Feature row: lane owns d in {4*lane..4*lane+3} and {256+4*lane..}
    const float4 f0 = *(const float4*)(f + lane * 4);
    const float4 f1 = *(const float4*)(f + 256 + lane * 4);

    // ||f||^2 (all lanes get the full sum)
    float ff = f0.x*f0.x + f0.y*f0.y + f0.z*f0.z + f0.w*f0.w
             + f1.x*f1.x + f1.y*f1.y + f1.z*f1.z + f1.w*f1.w;
    ff = wave_sum(ff);

    // Per-lane holders for "my" prototype (prototype index == lane)
    float s_dot = 0.f, s_pp = 0.f, s_l1 = 0.f;

    for (int p = 0; p < P; ++p) {
        const float* row = pr + p * D;
        const float4 q0 = *(const float4*)(row + lane * 4);
        const float4 q1 = *(const float4*)(row + 256 + lane * 4);

        float dot, pp, l1, t;
        dot  = f0.x*q0.x; pp  = q0.x*q0.x; t = f0.x - q0.x; l1  = fabsf(t);
        dot += f0.y*q0.y; pp += q0.y*q0.y; t = f0.y - q0.y; l1 += fabsf(t);
        dot += f0.z*q0.z; pp += q0.z*q0.z; t = f0.z - q0.z; l1 += fabsf(t);
        dot += f0.w*q0.w; pp += q0.w*q0.w; t = f0.w - q0.w; l1 += fabsf(t);
        dot += f1.x*q1.x; pp += q1.x*q1.x; t = f1.x - q1.x; l1 += fabsf(t);
        dot += f1.y*q1.y; pp += q1.y*q1.y; t = f1.y - q1.y; l1 += fabsf(t);
        dot += f1.z*q1.z; pp += q1.z*q1.z; t = f1.z - q1.z; l1 += fabsf(t);
        dot += f1.w*q1.w; pp += q1.w*q1.w; t = f1.w - q1.w; l1 += fabsf(t);

        // Full butterfly: every lane ends with the total; lane p keeps it.
#pragma unroll
        for (int m = 32; m >= 1; m >>= 1) {
            dot += __shfl_xor(dot, m, 64);
            pp  += __shfl_xor(pp,  m, 64);
            l1  += __shfl_xor(l1,  m, 64);
        }
        if (lane == p) { s_dot = dot; s_pp = pp; s_l1 = l1; }
    }

    // Distances for "my" prototype (index = lane)
    const float fnorm = fmaxf(sqrtf(ff),   EPS_COS);
    const float pnorm = fmaxf(sqrtf(s_pp), EPS_COS);
    const float d_cos = 1.0f - s_dot / (fnorm * pnorm);
    const float d_l1  = s_l1 * (1.0f / (float)D);
    const float d_l2  = (ff - 2.0f * s_dot + s_pp) * (1.0f / (float)D);

    // logits = 1/(d + 1e-5); stable softmax across the 64 lanes, x3, averaged
    float s[3];
    s[0] = 1.0f / (d_cos + EPS_INV);
    s[1] = 1.0f / (d_l1  + EPS_INV);
    s[2] = 1.0f / (d_l2  + EPS_INV);

    float prob = 0.f;
#pragma unroll
    for (int i = 0; i < 3; ++i) {
        float m = s[i];
#pragma unroll
        for (int w = 32; w >= 1; w >>= 1) m = fmaxf(m, __shfl_xor(m, w, 64));
        const float e = expf(s[i] - m);
        const float denom = wave_sum(e);
        prob += e / denom;
    }
    prob *= (1.0f / 3.0f);

    // argmax over lanes, first-index tie-break (matches jnp.argmax)
    float best = prob;
    int   bidx = lane;
#pragma unroll
    for (int w = 32; w >= 1; w >>= 1) {
        const float ov = __shfl_xor(best, w, 64);
        const int   oi = __shfl_xor(bidx, w, 64);
        if (ov > best || (ov == best && oi < bidx)) { best = ov; bidx = oi; }
    }

    // Outputs: labels (as float) at [0, N), probs at [N, N + N*P)
    out[(size_t)N + (size_t)n * P + lane] = prob;
    if (lane == 0) {
        out[n] = (float)proto_labels[cls * P + bidx];
    }
}

extern "C" void kernel_launch(void* const* d_in, const int* in_sizes, int n_in,
                              void* d_out, int out_size, void* d_ws, size_t ws_size,
                              hipStream_t stream) {
    const float* feats        = (const float*)d_in[0];
    const float* protos       = (const float*)d_in[1];
    const int*   cls_ids      = (const int*)d_in[2];
    const int*   proto_labels = (const int*)d_in[3];
    float* out = (float*)d_out;

    const int N = in_sizes[2];          // cls_ids count
    const int blocks = (N + WPB - 1) / WPB;
    proto_probs_kernel<<<blocks, WPB * 64, 0, stream>>>(
        feats, protos, cls_ids, proto_labels, out, N);
}

// Round 2
// 104.341 us; speedup vs baseline: 1.2681x; 1.2681x over previous
//
#include <hip/hip_runtime.h>

// Problem constants (from reference): N=4096, D=512, C=100, P=64
#define D 512
#define P 64
#define WPB 4           // waves per block -> block = 256 threads
#define EPS_COS 1e-8f
#define EPS_INV 1e-5f

__device__ __forceinline__ float wave_sum(float v) {
#pragma unroll
    for (int m = 32; m >= 1; m >>= 1) v += __shfl_xor(v, m, 64);
    return v;
}

// Kernel A: pp[r] = ||protos[r]||^2 for r in [0, C*P)
__global__ __launch_bounds__(256) void proto_norm_kernel(
    const float* __restrict__ protos, float* __restrict__ pp, int rows)
{
    const int lane = threadIdx.x & 63;
    const int wave = threadIdx.x >> 6;
    const int r = blockIdx.x * WPB + wave;
    if (r >= rows) return;
    const float* row = protos + (size_t)r * D;
    const float4 a = *(const float4*)(row + lane * 4);
    const float4 b = *(const float4*)(row + 256 + lane * 4);
    float s = a.x*a.x + a.y*a.y + a.z*a.z + a.w*a.w
            + b.x*b.x + b.y*b.y + b.z*b.z + b.w*b.w;
    s = wave_sum(s);
    if (lane == 0) pp[r] = s;
}

// Kernel B: one wave per box. Prototypes processed in groups of 8 with a
// recursive-halving reduce-scatter (10 shuffles per quantity per group vs 48
// for per-proto butterflies). Lane l ends owning proto p(l)=8*(l&7)+((l>>3)&7).
__global__ __launch_bounds__(WPB * 64) void proto_probs_kernel(
    const float* __restrict__ feats,        // [N, D]
    const float* __restrict__ protos,       // [C, P, D]
    const int*   __restrict__ cls_ids,      // [N]
    const int*   __restrict__ proto_labels, // [C, P]
    const float* __restrict__ ppbuf,        // [C*P] ||p||^2
    float* __restrict__ out,                // [N] labels ++ [N, P] probs
    int N)
{
    const int lane = threadIdx.x & 63;
    const int wave = threadIdx.x >> 6;
    const int n = blockIdx.x * WPB + wave;
    if (n >= N) return;

    const int cls = cls_ids[n];
    const float* f  = feats  + (size_t)n * D;
    const float* pr = protos + (size_t)cls * (P * D);

    const float4 f0 = *(const float4*)(f + lane * 4);
    const float4 f1 = *(const float4*)(f + 256 + lane * 4);

    float ff = f0.x*f0.x + f0.y*f0.y + f0.z*f0.z + f0.w*f0.w
             + f1.x*f1.x + f1.y*f1.y + f1.z*f1.z + f1.w*f1.w;
    ff = wave_sum(ff);

    const int jsel = (lane >> 3) & 7;   // proto-within-group this lane ends with
    const int gown = lane & 7;          // group whose result this lane keeps
    const bool hi32 = (lane & 32) != 0;
    const bool hi16 = (lane & 16) != 0;
    const bool hi8  = (lane & 8)  != 0;

    float r_dot = 0.f, r_l1 = 0.f;

    for (int g = 0; g < 8; ++g) {
        float pd[8], pl[8];
#pragma unroll
        for (int j = 0; j < 8; ++j) {
            const float* row = pr + (size_t)(8 * g + j) * D;
            const float4 q0 = *(const float4*)(row + lane * 4);
            const float4 q1 = *(const float4*)(row + 256 + lane * 4);
            float dot, l1, t;
            dot  = f0.x*q0.x; t = f0.x - q0.x; l1  = fabsf(t);
            dot += f0.y*q0.y; t = f0.y - q0.y; l1 += fabsf(t);
            dot += f0.z*q0.z; t = f0.z - q0.z; l1 += fabsf(t);
            dot += f0.w*q0.w; t = f0.w - q0.w; l1 += fabsf(t);
            dot += f1.x*q1.x; t = f1.x - q1.x; l1 += fabsf(t);
            dot += f1.y*q1.y; t = f1.y - q1.y; l1 += fabsf(t);
            dot += f1.z*q1.z; t = f1.z - q1.z; l1 += fabsf(t);
            dot += f1.w*q1.w; t = f1.w - q1.w; l1 += fabsf(t);
            pd[j] = dot; pl[j] = l1;
        }
        // Halving step 1: distance 32, 8 -> 4 partials
#pragma unroll
        for (int k = 0; k < 4; ++k) {
            const float sd = hi32 ? pd[k] : pd[k + 4];
            const float sl = hi32 ? pl[k] : pl[k + 4];
            const float rd = __shfl_xor(sd, 32, 64);
            const float rl = __shfl_xor(sl, 32, 64);
            pd[k] = (hi32 ? pd[k + 4] : pd[k]) + rd;
            pl[k] = (hi32 ? pl[k + 4] : pl[k]) + rl;
        }
        // Halving step 2: distance 16, 4 -> 2
#pragma unroll
        for (int k = 0; k < 2; ++k) {
            const float sd = hi16 ? pd[k] : pd[k + 2];
            const float sl = hi16 ? pl[k] : pl[k + 2];
            const float rd = __shfl_xor(sd, 16, 64);
            const float rl = __shfl_xor(sl, 16, 64);
            pd[k] = (hi16 ? pd[k + 2] : pd[k]) + rd;
            pl[k] = (hi16 ? pl[k + 2] : pl[k]) + rl;
        }
        // Halving step 3: distance 8, 2 -> 1
        {
            const float sd = hi8 ? pd[0] : pd[1];
            const float sl = hi8 ? pl[0] : pl[1];
            const float rd = __shfl_xor(sd, 8, 64);
            const float rl = __shfl_xor(sl, 8, 64);
            pd[0] = (hi8 ? pd[1] : pd[0]) + rd;
            pl[0] = (hi8 ? pl[1] : pl[0]) + rl;
        }
        // Finish: butterfly over distances 4,2,1
#pragma unroll
        for (int m = 4; m >= 1; m >>= 1) {
            pd[0] += __shfl_xor(pd[0], m, 64);
            pl[0] += __shfl_xor(pl[0], m, 64);
        }
        if (gown == g) { r_dot = pd[0]; r_l1 = pl[0]; }
    }

    const int myp = 8 * gown + jsel;    // proto index this lane owns
    const float s_pp = ppbuf[cls * P + myp];

    const float fnorm = fmaxf(sqrtf(ff),   EPS_COS);
    const float pnorm = fmaxf(sqrtf(s_pp), EPS_COS);
    const float d_cos = 1.0f - r_dot / (fnorm * pnorm);
    const float d_l1  = r_l1 * (1.0f / (float)D);
    const float d_l2  = (ff - 2.0f * r_dot + s_pp) * (1.0f / (float)D);

    float s[3];
    s[0] = 1.0f / (d_cos + EPS_INV);
    s[1] = 1.0f / (d_l1  + EPS_INV);
    s[2] = 1.0f / (d_l2  + EPS_INV);

    float prob = 0.f;
#pragma unroll
    for (int i = 0; i < 3; ++i) {
        float m = s[i];
#pragma unroll
        for (int w = 32; w >= 1; w >>= 1) m = fmaxf(m, __shfl_xor(m, w, 64));
        const float e = expf(s[i] - m);
        const float denom = wave_sum(e);
        prob += e / denom;
    }
    prob *= (1.0f / 3.0f);

    // argmax over protos, first-index tie-break (compare true proto indices)
    float best = prob;
    int   bidx = myp;
#pragma unroll
    for (int w = 32; w >= 1; w >>= 1) {
        const float ov = __shfl_xor(best, w, 64);
        const int   oi = __shfl_xor(bidx, w, 64);
        if (ov > best || (ov == best && oi < bidx)) { best = ov; bidx = oi; }
    }

    out[(size_t)N + (size_t)n * P + myp] = prob;
    if (lane == 0) {
        out[n] = (float)proto_labels[cls * P + bidx];
    }
}

extern "C" void kernel_launch(void* const* d_in, const int* in_sizes, int n_in,
                              void* d_out, int out_size, void* d_ws, size_t ws_size,
                              hipStream_t stream) {
    const float* feats        = (const float*)d_in[0];
    const float* protos       = (const float*)d_in[1];
    const int*   cls_ids      = (const int*)d_in[2];
    const int*   proto_labels = (const int*)d_in[3];
    float* out = (float*)d_out;
    float* pp  = (float*)d_ws;          // C*P floats (25.6 KB)

    const int N    = in_sizes[2];           // 4096
    const int rows = in_sizes[1] / D;       // C*P = 6400

    proto_norm_kernel<<<(rows + WPB - 1) / WPB, WPB * 64, 0, stream>>>(
        protos, pp, rows);
    proto_probs_kernel<<<(N + WPB - 1) / WPB, WPB * 64, 0, stream>>>(
        feats, protos, cls_ids, proto_labels, pp, out, N);
}